// Round 2
// baseline (7438.895 us; speedup 1.0000x reference)
//
#include <hip/hip_runtime.h>
#include <math.h>

// Problem dims (fixed by reference setup_inputs)
#define BB 8
#define LL_ 2048
#define DD 1024
#define HH 2048

#define TS 128   // GEMM tile M and N
#define KS 16    // GEMM tile K

// ---------------------------------------------------------------------------
// GEMM NN: C[M,N] = A[M,K] @ B[K,N] (+bias, +relu). Row-major, lda=K, ldb=N,
// ldc=N. M,N multiples of 128; K multiple of 16. Batched via blockIdx.z with
// element strides. `causal_kend` != 0 limits K loop to min(K, i0+TS) (P@V
// with strictly causal P).
// ---------------------------------------------------------------------------
template <bool BIAS, bool RELU>
__global__ __launch_bounds__(256) void gemm_nn_kernel(
    const float* __restrict__ A, const float* __restrict__ B,
    const float* __restrict__ bias, float* __restrict__ C,
    int N, int K, int causal_kend,
    long sAz, long sBz, long sCz)
{
    __shared__ float As[KS][TS];  // transposed A tile: As[k][m]
    __shared__ float Bs[KS][TS];  // Bs[k][n]

    const int t  = threadIdx.x;
    const int tx = t & 15;        // 0..15 -> N direction
    const int ty = t >> 4;        // 0..15 -> M direction
    const int i0 = blockIdx.y * TS;
    const int n0 = blockIdx.x * TS;

    A += (long)blockIdx.z * sAz;
    B += (long)blockIdx.z * sBz;
    C += (long)blockIdx.z * sCz;

    int kend = K;
    if (causal_kend) { int ke = i0 + TS; kend = ke < K ? ke : K; }

    float acc[8][8];
    #pragma unroll
    for (int i = 0; i < 8; ++i)
        #pragma unroll
        for (int j = 0; j < 8; ++j) acc[i][j] = 0.f;

    for (int k0 = 0; k0 < kend; k0 += KS) {
        #pragma unroll
        for (int it = 0; it < 2; ++it) {
            int f = t + it * 256;          // 0..511
            int row = f >> 2;              // 0..127
            int c4  = (f & 3) << 2;        // 0,4,8,12
            const float4 av = *(const float4*)&A[(long)(i0 + row) * K + k0 + c4];
            As[c4 + 0][row] = av.x;
            As[c4 + 1][row] = av.y;
            As[c4 + 2][row] = av.z;
            As[c4 + 3][row] = av.w;
        }
        #pragma unroll
        for (int it = 0; it < 2; ++it) {
            int f = t + it * 256;
            int row = f >> 5;              // 0..15
            int c4  = (f & 31) << 2;       // 0..124
            *(float4*)&Bs[row][c4] = *(const float4*)&B[(long)(k0 + row) * N + n0 + c4];
        }
        __syncthreads();
        #pragma unroll
        for (int kk = 0; kk < KS; ++kk) {
            float a[8], b[8];
            *(float4*)&a[0] = *(const float4*)&As[kk][ty * 8];
            *(float4*)&a[4] = *(const float4*)&As[kk][ty * 8 + 4];
            *(float4*)&b[0] = *(const float4*)&Bs[kk][tx * 8];
            *(float4*)&b[4] = *(const float4*)&Bs[kk][tx * 8 + 4];
            #pragma unroll
            for (int i = 0; i < 8; ++i)
                #pragma unroll
                for (int j = 0; j < 8; ++j)
                    acc[i][j] = fmaf(a[i], b[j], acc[i][j]);
        }
        __syncthreads();
    }

    #pragma unroll
    for (int i = 0; i < 8; ++i) {
        long r = i0 + ty * 8 + i;
        #pragma unroll
        for (int jj = 0; jj < 8; jj += 4) {
            float4 v;
            float* vp = &v.x;
            #pragma unroll
            for (int j = 0; j < 4; ++j) {
                float val = acc[i][jj + j];
                if (BIAS) val += bias[n0 + tx * 8 + jj + j];
                if (RELU) val = val > 0.f ? val : 0.f;
                vp[j] = val;
            }
            *(float4*)&C[r * N + n0 + tx * 8 + jj] = v;
        }
    }
}

// ---------------------------------------------------------------------------
// GEMM NT for attention scores: S[i,j] = scale * sum_d Q[i,d]*K[j,d].
// Causal: blocks fully above the diagonal are skipped (softmax masks them
// without ever reading S there).
// ---------------------------------------------------------------------------
__global__ __launch_bounds__(256) void gemm_nt_kernel(
    const float* __restrict__ Q, const float* __restrict__ Km,
    float* __restrict__ S, int Lk, int D, float scale, int causal,
    long sQz, long sKz, long sSz)
{
    const int i0 = blockIdx.y * TS;
    const int j0 = blockIdx.x * TS;
    if (causal && j0 > i0 + (TS - 1)) return;  // fully masked block

    __shared__ float As[KS][TS];
    __shared__ float Bs[KS][TS];

    const int t  = threadIdx.x;
    const int tx = t & 15, ty = t >> 4;

    Q  += (long)blockIdx.z * sQz;
    Km += (long)blockIdx.z * sKz;
    S  += (long)blockIdx.z * sSz;

    float acc[8][8];
    #pragma unroll
    for (int i = 0; i < 8; ++i)
        #pragma unroll
        for (int j = 0; j < 8; ++j) acc[i][j] = 0.f;

    for (int k0 = 0; k0 < D; k0 += KS) {
        #pragma unroll
        for (int it = 0; it < 2; ++it) {
            int f = t + it * 256;
            int row = f >> 2, c4 = (f & 3) << 2;
            const float4 av = *(const float4*)&Q[(long)(i0 + row) * D + k0 + c4];
            As[c4 + 0][row] = av.x; As[c4 + 1][row] = av.y;
            As[c4 + 2][row] = av.z; As[c4 + 3][row] = av.w;
        }
        #pragma unroll
        for (int it = 0; it < 2; ++it) {
            int f = t + it * 256;
            int row = f >> 2, c4 = (f & 3) << 2;
            const float4 bv = *(const float4*)&Km[(long)(j0 + row) * D + k0 + c4];
            Bs[c4 + 0][row] = bv.x; Bs[c4 + 1][row] = bv.y;
            Bs[c4 + 2][row] = bv.z; Bs[c4 + 3][row] = bv.w;
        }
        __syncthreads();
        #pragma unroll
        for (int kk = 0; kk < KS; ++kk) {
            float a[8], b[8];
            *(float4*)&a[0] = *(const float4*)&As[kk][ty * 8];
            *(float4*)&a[4] = *(const float4*)&As[kk][ty * 8 + 4];
            *(float4*)&b[0] = *(const float4*)&Bs[kk][tx * 8];
            *(float4*)&b[4] = *(const float4*)&Bs[kk][tx * 8 + 4];
            #pragma unroll
            for (int i = 0; i < 8; ++i)
                #pragma unroll
                for (int j = 0; j < 8; ++j)
                    acc[i][j] = fmaf(a[i], b[j], acc[i][j]);
        }
        __syncthreads();
    }

    #pragma unroll
    for (int i = 0; i < 8; ++i) {
        long r = i0 + ty * 8 + i;
        #pragma unroll
        for (int jj = 0; jj < 8; jj += 4) {
            float4 v;
            v.x = acc[i][jj + 0] * scale;
            v.y = acc[i][jj + 1] * scale;
            v.z = acc[i][jj + 2] * scale;
            v.w = acc[i][jj + 3] * scale;
            *(float4*)&S[r * Lk + j0 + tx * 8 + jj] = v;
        }
    }
}

// ---------------------------------------------------------------------------
// Row softmax over L=2048 columns; one 256-thread block per row. Causal mask
// applied here (masked entries never read -> skipped score blocks are safe).
// ---------------------------------------------------------------------------
__global__ __launch_bounds__(256) void softmax_kernel(
    float* __restrict__ S, int L, int causal, long sSz)
{
    const int i = blockIdx.x;
    float* row = S + (long)blockIdx.y * sSz + (long)i * L;
    const int t = threadIdx.x;

    float v[8];
    float m = -INFINITY;
    #pragma unroll
    for (int k = 0; k < 8; ++k) {
        int j = t + k * 256;
        float val = -INFINITY;
        if (!(causal && j > i)) val = row[j];
        v[k] = val;
        m = fmaxf(m, val);
    }
    #pragma unroll
    for (int o = 32; o > 0; o >>= 1) m = fmaxf(m, __shfl_down(m, o, 64));
    __shared__ float redm[4];
    if ((t & 63) == 0) redm[t >> 6] = m;
    __syncthreads();
    m = fmaxf(fmaxf(redm[0], redm[1]), fmaxf(redm[2], redm[3]));

    float sum = 0.f;
    #pragma unroll
    for (int k = 0; k < 8; ++k) {
        float e = expf(v[k] - m);
        v[k] = e;
        sum += e;
    }
    #pragma unroll
    for (int o = 32; o > 0; o >>= 1) sum += __shfl_down(sum, o, 64);
    __shared__ float reds[4];
    if ((t & 63) == 0) reds[t >> 6] = sum;
    __syncthreads();
    sum = reds[0] + reds[1] + reds[2] + reds[3];

    const float inv = 1.0f / sum;
    #pragma unroll
    for (int k = 0; k < 8; ++k) row[t + k * 256] = v[k] * inv;
}

// ---------------------------------------------------------------------------
// out[r,:] = LayerNorm(x[r,:] + y[r,:]; gamma, beta, eps=1e-3), D=1024.
// ---------------------------------------------------------------------------
__global__ __launch_bounds__(256) void add_ln_kernel(
    const float* __restrict__ X, const float* __restrict__ Y,
    const float* __restrict__ gamma, const float* __restrict__ beta,
    float* __restrict__ out, int D)
{
    const long r = blockIdx.x;
    const int t = threadIdx.x;
    const float4 x = *(const float4*)&X[r * D + t * 4];
    const float4 y = *(const float4*)&Y[r * D + t * 4];
    float s0 = x.x + y.x, s1 = x.y + y.y, s2 = x.z + y.z, s3 = x.w + y.w;

    float sum = s0 + s1 + s2 + s3;
    float sq  = s0 * s0 + s1 * s1 + s2 * s2 + s3 * s3;
    #pragma unroll
    for (int o = 32; o > 0; o >>= 1) {
        sum += __shfl_down(sum, o, 64);
        sq  += __shfl_down(sq, o, 64);
    }
    __shared__ float rsum[4], rsq[4];
    if ((t & 63) == 0) { rsum[t >> 6] = sum; rsq[t >> 6] = sq; }
    __syncthreads();
    sum = rsum[0] + rsum[1] + rsum[2] + rsum[3];
    sq  = rsq[0] + rsq[1] + rsq[2] + rsq[3];

    const float mu  = sum / (float)D;
    const float var = sq / (float)D - mu * mu;
    const float rstd = rsqrtf(var + 1e-3f);

    const float4 g = *(const float4*)&gamma[t * 4];
    const float4 b = *(const float4*)&beta[t * 4];
    float4 o;
    o.x = (s0 - mu) * rstd * g.x + b.x;
    o.y = (s1 - mu) * rstd * g.y + b.y;
    o.z = (s2 - mu) * rstd * g.z + b.z;
    o.w = (s3 - mu) * rstd * g.w + b.w;
    *(float4*)&out[r * D + t * 4] = o;
}

// ---------------------------------------------------------------------------
extern "C" void kernel_launch(void* const* d_in, const int* in_sizes, int n_in,
                              void* d_out, int out_size, void* d_ws, size_t ws_size,
                              hipStream_t stream)
{
    const int B = BB, L = LL_, D = DD, H = HH;
    const long LD  = (long)L * D;        // 2M elems
    const long LLs = (long)L * L;        // 4M elems
    const long BLD = (long)B * LD;       // 16.78M elems
    const int  BL  = B * L;              // 16384

    const float* x     = (const float*)d_in[0];
    const float* ctx   = (const float*)d_in[1];
    const float* Wk_s  = (const float*)d_in[2];
    const float* Wv_s  = (const float*)d_in[3];
    const float* Wq_s  = (const float*)d_in[4];
    const float* Wk_c  = (const float*)d_in[5];
    const float* Wv_c  = (const float*)d_in[6];
    const float* Wq_c  = (const float*)d_in[7];
    const float* W1    = (const float*)d_in[8];
    const float* b1    = (const float*)d_in[9];
    const float* W2    = (const float*)d_in[10];
    const float* b2    = (const float*)d_in[11];
    const float* gamma = (const float*)d_in[12];
    const float* beta  = (const float*)d_in[13];
    float* out = (float*)d_out;

    // ---- Workspace budget (adaptive; never exceed ws_size) ----
    // Layout: o2 [BLD] | scratch [g*(4*LD + LLs)]
    //   scratch per batch-group: q,k,v,attn (g*LD each) + scores (g*LLs)
    // o1 lives in d_out (dead before the final store; fully rewritten each call).
    const long ws_f = (long)(ws_size / sizeof(float));
    const long per_b = 4 * LD + LLs;     // 12M elems per batch of group
    long gl = (ws_f - BLD) / per_b;
    int g = gl < 1 ? 1 : (gl > B ? B : (int)gl);

    float* o2      = (float*)d_ws;
    float* scratch = o2 + BLD;
    float* q    = scratch;
    float* k    = q + (long)g * LD;
    float* v    = k + (long)g * LD;
    float* attn = v + (long)g * LD;
    float* s    = attn + (long)g * LD;
    float* o1   = out;                   // d_out doubles as o1 scratch

    const float scale = 1.0f / sqrtf((float)L);
    const dim3 blk(256);

    // Attention phase: per batch-group projections + scores + softmax + PV + LN.
    // qsrc rows are [BL, D] (per-batch stride LD); ksrc/vsrc likewise.
    auto attn_phase = [&](const float* qsrc, const float* ksrc, const float* vsrc,
                          const float* Wq, const float* Wk, const float* Wv,
                          const float* resid, float* dst, int causal) {
        for (int b0 = 0; b0 < B; b0 += g) {
            const int gb = (B - b0) < g ? (B - b0) : g;
            const long off = (long)b0 * LD;
            // projections over gb*L contiguous rows
            gemm_nn_kernel<false, false><<<dim3(D / TS, gb * L / TS, 1), blk, 0, stream>>>(
                qsrc + off, Wq, nullptr, q, D, D, 0, 0, 0, 0);
            gemm_nn_kernel<false, false><<<dim3(D / TS, gb * L / TS, 1), blk, 0, stream>>>(
                ksrc + off, Wk, nullptr, k, D, D, 0, 0, 0, 0);
            gemm_nn_kernel<false, false><<<dim3(D / TS, gb * L / TS, 1), blk, 0, stream>>>(
                vsrc + off, Wv, nullptr, v, D, D, 0, 0, 0, 0);
            // scores + softmax + PV, z-batched over gb
            gemm_nt_kernel<<<dim3(L / TS, L / TS, gb), blk, 0, stream>>>(
                q, k, s, L, D, scale, causal, LD, LD, LLs);
            softmax_kernel<<<dim3(L, gb), blk, 0, stream>>>(s, L, causal, LLs);
            gemm_nn_kernel<false, false><<<dim3(D / TS, L / TS, gb), blk, 0, stream>>>(
                s, v, nullptr, attn, D, L, causal, LLs, LD, LD);
            // residual + LN
            add_ln_kernel<<<dim3(gb * L), blk, 0, stream>>>(
                resid + off, attn, gamma, beta, dst + off, D);
        }
    };

    // ---- Phase A: causal self-attention + residual + LN -> o1 (in d_out) ----
    attn_phase(x, x, x, Wq_s, Wk_s, Wv_s, x, o1, 1);

    // ---- Phase B: cross-attention (Q from o1, K/V from ctx) + LN -> o2 ----
    attn_phase(o1, ctx, ctx, Wq_c, Wk_c, Wv_c, o1, o2, 0);

    // ---- Phase C: FFN + LN -> out, row-chunked through scratch ----
    {
        const long scratch_f = (long)g * per_b;
        long mc = scratch_f / (H + D);
        mc = (mc / TS) * TS;
        if (mc > BL) mc = BL;
        if (mc < TS) mc = TS;  // needs >= 128 rows (3M floats); minimum config has 12M
        for (long m0 = 0; m0 < BL; m0 += mc) {
            const long rows = (BL - m0) < mc ? (BL - m0) : mc;
            float* h   = scratch;             // [rows, H]
            float* ffo = scratch + rows * H;  // [rows, D]
            gemm_nn_kernel<true, true><<<dim3(H / TS, rows / TS, 1), blk, 0, stream>>>(
                o2 + m0 * D, W1, b1, h, H, D, 0, 0, 0, 0);
            gemm_nn_kernel<true, false><<<dim3(D / TS, rows / TS, 1), blk, 0, stream>>>(
                h, W2, b2, ffo, D, H, 0, 0, 0, 0);
            add_ln_kernel<<<dim3(rows), blk, 0, stream>>>(
                o2 + m0 * D, ffo, gamma, beta, out + m0 * D, D);
        }
    }
}

// Round 3
// 1621.582 us; speedup vs baseline: 4.5874x; 4.5874x over previous
//
#include <hip/hip_runtime.h>
#include <math.h>

// Problem dims (fixed by reference setup_inputs)
#define BB 8
#define LL_ 2048
#define DD 1024
#define HH 2048

typedef unsigned short u16;
typedef __attribute__((ext_vector_type(8))) u16 u16x8;
typedef __attribute__((ext_vector_type(4))) u16 u16x4;
typedef __attribute__((ext_vector_type(8))) __bf16 bf16x8;
typedef __attribute__((ext_vector_type(4))) float f32x4;

__device__ __forceinline__ u16 f2bf(float f) {
    union { float f; unsigned u; } v; v.f = f;
    unsigned r = (v.u + 0x7FFFu + ((v.u >> 16) & 1u)) >> 16;
    return (u16)r;
}
__device__ __forceinline__ float bf2f(u16 h) {
    union { unsigned u; float f; } v; v.u = ((unsigned)h) << 16;
    return v.f;
}

// ---------------------------------------------------------------------------
// bf16 MFMA GEMM, NT form: C[M,N] = A[M,K] @ Bt[N,K]^T.  A, Bt row-major bf16
// (u16 storage), fp32 accumulate, OutT output (float or u16/bf16).
// 128x128 tile, BK=32, 256 threads = 4 waves (2x2), each wave 64x64 via
// 4x4 frags of v_mfma_f32_16x16x32_bf16. Reg-staged LDS, linear layout.
// CSKIP: skip blocks fully above the causal diagonal (scores).
// CKEND: limit K loop to i0+128 (P@V with strictly-causal P).
// Batched via blockIdx.z with element strides.
// ---------------------------------------------------------------------------
template <typename OutT, bool BIAS, bool RELU, bool CSKIP, bool CKEND>
__global__ __launch_bounds__(256) void gemm_bf16_kernel(
    const u16* __restrict__ A, const u16* __restrict__ Bt,
    const float* __restrict__ bias, OutT* __restrict__ C,
    int K, int N, float scale, long sAz, long sBz, long sCz)
{
    const int i0 = blockIdx.y * 128;   // M block
    const int n0 = blockIdx.x * 128;   // N block
    if (CSKIP && n0 > i0 + 127) return;

    A  += (long)blockIdx.z * sAz;
    Bt += (long)blockIdx.z * sBz;
    C  += (long)blockIdx.z * sCz;

    __shared__ u16 As[128 * 32];
    __shared__ u16 Bs[128 * 32];

    int kend = K;
    if (CKEND) { int ke = i0 + 128; kend = ke < K ? ke : K; }

    const int t   = threadIdx.x;
    const int wid = t >> 6, l = t & 63;
    const int wr  = wid >> 1, wc = wid & 1;   // wave 2x2 -> 64x64 each
    const int lg  = l >> 4, lr = l & 15;

    // staging: thread t covers (row = t>>2 [+64], k = (t&3)*8); LDS offset t*8
    const int srow  = t >> 2;
    const int skoff = (t & 3) * 8;
    const u16* ga = A  + (long)(i0 + srow) * K + skoff;
    const u16* gb = Bt + (long)(n0 + srow) * K + skoff;
    u16* la = As + t * 8;
    u16* lb = Bs + t * 8;

    f32x4 acc[4][4];
    #pragma unroll
    for (int m = 0; m < 4; ++m)
        #pragma unroll
        for (int n = 0; n < 4; ++n)
            acc[m][n] = (f32x4){0.f, 0.f, 0.f, 0.f};

    for (int k0 = 0; k0 < kend; k0 += 32) {
        const u16x8 ra0 = *(const u16x8*)(ga + k0);
        const u16x8 ra1 = *(const u16x8*)(ga + (long)64 * K + k0);
        const u16x8 rb0 = *(const u16x8*)(gb + k0);
        const u16x8 rb1 = *(const u16x8*)(gb + (long)64 * K + k0);
        __syncthreads();   // previous iteration's LDS reads complete
        *(u16x8*)la = ra0;
        *(u16x8*)(la + 64 * 32) = ra1;
        *(u16x8*)lb = rb0;
        *(u16x8*)(lb + 64 * 32) = rb1;
        __syncthreads();

        bf16x8 af[4], bfr[4];
        #pragma unroll
        for (int m = 0; m < 4; ++m)
            af[m] = *(bf16x8*)(As + (wr * 64 + m * 16 + lr) * 32 + lg * 8);
        #pragma unroll
        for (int n = 0; n < 4; ++n)
            bfr[n] = *(bf16x8*)(Bs + (wc * 64 + n * 16 + lr) * 32 + lg * 8);
        #pragma unroll
        for (int m = 0; m < 4; ++m)
            #pragma unroll
            for (int n = 0; n < 4; ++n)
                acc[m][n] = __builtin_amdgcn_mfma_f32_16x16x32_bf16(
                    af[m], bfr[n], acc[m][n], 0, 0, 0);
    }

    // epilogue: C frag mapping col = lane&15, row = (lane>>4)*4 + r
    #pragma unroll
    for (int n = 0; n < 4; ++n) {
        const int col = n0 + wc * 64 + n * 16 + lr;
        const float bv = BIAS ? bias[col] : 0.f;
        #pragma unroll
        for (int m = 0; m < 4; ++m) {
            const int row0 = i0 + wr * 64 + m * 16 + lg * 4;
            #pragma unroll
            for (int r = 0; r < 4; ++r) {
                float val = acc[m][n][r] * scale + bv;
                if (RELU) val = fmaxf(val, 0.f);
                if (sizeof(OutT) == 4) {
                    ((float*)C)[(long)(row0 + r) * N + col] = val;
                } else {
                    ((u16*)C)[(long)(row0 + r) * N + col] = f2bf(val);
                }
            }
        }
    }
}

// ---------------------------------------------------------------------------
// fp32 -> bf16 elementwise convert (n multiple of 2048)
// ---------------------------------------------------------------------------
__global__ __launch_bounds__(256) void f2b_kernel(
    const float* __restrict__ in, u16* __restrict__ out)
{
    const long i = ((long)blockIdx.x * 256 + threadIdx.x) * 8;
    const float4 a = *(const float4*)(in + i);
    const float4 b = *(const float4*)(in + i + 4);
    u16x8 o;
    o[0] = f2bf(a.x); o[1] = f2bf(a.y); o[2] = f2bf(a.z); o[3] = f2bf(a.w);
    o[4] = f2bf(b.x); o[5] = f2bf(b.y); o[6] = f2bf(b.z); o[7] = f2bf(b.w);
    *(u16x8*)(out + i) = o;
}

// ---------------------------------------------------------------------------
// transpose fp32 [R][C] -> bf16 [C][R]  (weights; R,C multiples of 32)
// ---------------------------------------------------------------------------
__global__ __launch_bounds__(256) void transpose_f2b_kernel(
    const float* __restrict__ in, u16* __restrict__ out, int R, int C)
{
    __shared__ float tile[32][33];
    const int tx = threadIdx.x & 31, ty = threadIdx.x >> 5;
    const int c0 = blockIdx.x * 32, r0 = blockIdx.y * 32;
    #pragma unroll
    for (int i = 0; i < 4; ++i)
        tile[ty + i * 8][tx] = in[(long)(r0 + ty + i * 8) * C + c0 + tx];
    __syncthreads();
    #pragma unroll
    for (int i = 0; i < 4; ++i)
        out[(long)(c0 + ty + i * 8) * R + r0 + tx] = f2bf(tile[tx][ty + i * 8]);
}

// ---------------------------------------------------------------------------
// transpose bf16 [R][C] -> bf16 [C][R], z-batched (V transpose)
// ---------------------------------------------------------------------------
__global__ __launch_bounds__(256) void transpose_b2b_kernel(
    const u16* __restrict__ in, u16* __restrict__ out, int R, int C,
    long sIz, long sOz)
{
    __shared__ u16 tile[32][33];
    in  += (long)blockIdx.z * sIz;
    out += (long)blockIdx.z * sOz;
    const int tx = threadIdx.x & 31, ty = threadIdx.x >> 5;
    const int c0 = blockIdx.x * 32, r0 = blockIdx.y * 32;
    #pragma unroll
    for (int i = 0; i < 4; ++i)
        tile[ty + i * 8][tx] = in[(long)(r0 + ty + i * 8) * C + c0 + tx];
    __syncthreads();
    #pragma unroll
    for (int i = 0; i < 4; ++i)
        out[(long)(c0 + ty + i * 8) * R + r0 + tx] = tile[tx][ty + i * 8];
}

// ---------------------------------------------------------------------------
// Row softmax on bf16 scores in place (-> probabilities bf16). fp32 math.
// Causal mask applied by index (garbage in skipped blocks never used).
// ---------------------------------------------------------------------------
__global__ __launch_bounds__(256) void softmax_bf16_kernel(
    u16* __restrict__ S, int L, int causal, long sSz)
{
    const int i = blockIdx.x;
    u16* row = S + (long)blockIdx.y * sSz + (long)i * L;
    const int t = threadIdx.x;

    const u16x8 rv = *(const u16x8*)(row + t * 8);
    float v[8];
    float m = -INFINITY;
    #pragma unroll
    for (int e = 0; e < 8; ++e) {
        const int j = t * 8 + e;
        float val = (causal && j > i) ? -INFINITY : bf2f(rv[e]);
        v[e] = val;
        m = fmaxf(m, val);
    }
    #pragma unroll
    for (int o = 32; o > 0; o >>= 1) m = fmaxf(m, __shfl_down(m, o, 64));
    __shared__ float redm[4];
    if ((t & 63) == 0) redm[t >> 6] = m;
    __syncthreads();
    m = fmaxf(fmaxf(redm[0], redm[1]), fmaxf(redm[2], redm[3]));

    float sum = 0.f;
    #pragma unroll
    for (int e = 0; e < 8; ++e) { float ex = expf(v[e] - m); v[e] = ex; sum += ex; }
    #pragma unroll
    for (int o = 32; o > 0; o >>= 1) sum += __shfl_down(sum, o, 64);
    __shared__ float reds[4];
    if ((t & 63) == 0) reds[t >> 6] = sum;
    __syncthreads();
    sum = reds[0] + reds[1] + reds[2] + reds[3];

    const float inv = 1.0f / sum;
    u16x8 ov;
    #pragma unroll
    for (int e = 0; e < 8; ++e) ov[e] = f2bf(v[e] * inv);
    *(u16x8*)(row + t * 8) = ov;
}

// ---------------------------------------------------------------------------
// out = LayerNorm(x + y; gamma, beta, eps=1e-3), D=1024; optional bf16 copy.
// ---------------------------------------------------------------------------
__global__ __launch_bounds__(256) void add_ln_kernel(
    const float* __restrict__ X, const float* __restrict__ Y,
    const float* __restrict__ gamma, const float* __restrict__ beta,
    float* __restrict__ out, u16* __restrict__ outb, int D)
{
    const long r = blockIdx.x;
    const int t = threadIdx.x;
    const float4 x = *(const float4*)&X[r * D + t * 4];
    const float4 y = *(const float4*)&Y[r * D + t * 4];
    float s0 = x.x + y.x, s1 = x.y + y.y, s2 = x.z + y.z, s3 = x.w + y.w;

    float sum = s0 + s1 + s2 + s3;
    float sq  = s0 * s0 + s1 * s1 + s2 * s2 + s3 * s3;
    #pragma unroll
    for (int o = 32; o > 0; o >>= 1) {
        sum += __shfl_down(sum, o, 64);
        sq  += __shfl_down(sq, o, 64);
    }
    __shared__ float rsum[4], rsq[4];
    if ((t & 63) == 0) { rsum[t >> 6] = sum; rsq[t >> 6] = sq; }
    __syncthreads();
    sum = rsum[0] + rsum[1] + rsum[2] + rsum[3];
    sq  = rsq[0] + rsq[1] + rsq[2] + rsq[3];

    const float mu   = sum / (float)D;
    const float var  = sq / (float)D - mu * mu;
    const float rstd = rsqrtf(var + 1e-3f);

    const float4 g = *(const float4*)&gamma[t * 4];
    const float4 b = *(const float4*)&beta[t * 4];
    float4 o;
    o.x = (s0 - mu) * rstd * g.x + b.x;
    o.y = (s1 - mu) * rstd * g.y + b.y;
    o.z = (s2 - mu) * rstd * g.z + b.z;
    o.w = (s3 - mu) * rstd * g.w + b.w;
    *(float4*)&out[r * D + t * 4] = o;
    if (outb) {
        u16x4 ob;
        ob[0] = f2bf(o.x); ob[1] = f2bf(o.y); ob[2] = f2bf(o.z); ob[3] = f2bf(o.w);
        *(u16x4*)&outb[r * D + t * 4] = ob;
    }
}

// ---------------------------------------------------------------------------
extern "C" void kernel_launch(void* const* d_in, const int* in_sizes, int n_in,
                              void* d_out, int out_size, void* d_ws, size_t ws_size,
                              hipStream_t stream)
{
    const int B = BB, L = LL_, D = DD, H = HH;
    const long LD  = (long)L * D;        // 2M elems
    const long LLs = (long)L * L;        // 4M elems
    const long BLD = (long)B * LD;       // 16.78M elems
    const int  BL  = B * L;              // 16384

    const float* x     = (const float*)d_in[0];
    const float* ctx   = (const float*)d_in[1];
    const float* Wk_s  = (const float*)d_in[2];
    const float* Wv_s  = (const float*)d_in[3];
    const float* Wq_s  = (const float*)d_in[4];
    const float* Wk_c  = (const float*)d_in[5];
    const float* Wv_c  = (const float*)d_in[6];
    const float* Wq_c  = (const float*)d_in[7];
    const float* W1    = (const float*)d_in[8];
    const float* b1    = (const float*)d_in[9];
    const float* W2    = (const float*)d_in[10];
    const float* b2    = (const float*)d_in[11];
    const float* gamma = (const float*)d_in[12];
    const float* beta  = (const float*)d_in[13];
    float* out = (float*)d_out;

    // ---- workspace layout (bump allocator) ----
    size_t ofs = 0;
    auto alloc = [&](size_t bytes) -> char* {
        char* p = (char*)d_ws + ofs;
        ofs += (bytes + 255) & ~(size_t)255;
        return p;
    };
    u16* WkTs = (u16*)alloc((size_t)D * D * 2);
    u16* WvTs = (u16*)alloc((size_t)D * D * 2);
    u16* WqTs = (u16*)alloc((size_t)D * D * 2);
    u16* WkTc = (u16*)alloc((size_t)D * D * 2);
    u16* WvTc = (u16*)alloc((size_t)D * D * 2);
    u16* WqTc = (u16*)alloc((size_t)D * D * 2);
    u16* W1T  = (u16*)alloc((size_t)D * H * 2);   // [H][D]
    u16* W2T  = (u16*)alloc((size_t)H * D * 2);   // [D][H]
    u16* actb1 = (u16*)alloc((size_t)BLD * 2);    // xb -> ctxb -> o2b
    u16* actb2 = (u16*)alloc((size_t)BLD * 2);    // o1b
    float* o2  = (float*)alloc((size_t)BLD * 4);
    char* scratch = (char*)d_ws + ofs;
    const size_t remain = ws_size > ofs ? ws_size - ofs : 0;

    // attention batch-group scratch: q,k,v,vt (bf16 LD each) + P (bf16 LLs)
    // + attn (fp32 LD) per batch
    const size_t per_b = (size_t)(4 * LD + LLs) * 2 + (size_t)LD * 4;
    long gl = (long)(remain / per_b);
    const int g = gl < 1 ? 1 : (gl > B ? B : (int)gl);

    u16* qb  = (u16*)scratch;
    u16* kb  = qb + (size_t)g * LD;
    u16* vb  = kb + (size_t)g * LD;
    u16* vtb = vb + (size_t)g * LD;
    u16* Pb  = vtb + (size_t)g * LD;
    float* attnb = (float*)(Pb + (size_t)g * LLs);

    const float scale = 1.0f / sqrtf((float)L);
    const dim3 blk(256);

    // ---- weight transposes (fp32 -> bf16, [K][N] -> [N][K]) ----
    transpose_f2b_kernel<<<dim3(D/32, D/32), blk, 0, stream>>>(Wk_s, WkTs, D, D);
    transpose_f2b_kernel<<<dim3(D/32, D/32), blk, 0, stream>>>(Wv_s, WvTs, D, D);
    transpose_f2b_kernel<<<dim3(D/32, D/32), blk, 0, stream>>>(Wq_s, WqTs, D, D);
    transpose_f2b_kernel<<<dim3(D/32, D/32), blk, 0, stream>>>(Wk_c, WkTc, D, D);
    transpose_f2b_kernel<<<dim3(D/32, D/32), blk, 0, stream>>>(Wv_c, WvTc, D, D);
    transpose_f2b_kernel<<<dim3(D/32, D/32), blk, 0, stream>>>(Wq_c, WqTc, D, D);
    transpose_f2b_kernel<<<dim3(H/32, D/32), blk, 0, stream>>>(W1, W1T, D, H);
    transpose_f2b_kernel<<<dim3(D/32, H/32), blk, 0, stream>>>(W2, W2T, H, D);

    // attention phase: per batch-group proj + scores + softmax + PV + add/LN
    auto attn_phase = [&](const u16* qsrcb, const u16* kvsrcb,
                          const u16* WqT, const u16* WkT, const u16* WvT,
                          const float* resid, float* dst, u16* dstb, int causal) {
        for (int b0 = 0; b0 < B; b0 += g) {
            const int gb = (B - b0) < g ? (B - b0) : g;
            const long off = (long)b0 * LD;
            gemm_bf16_kernel<u16, false, false, false, false>
                <<<dim3(D/128, gb*L/128), blk, 0, stream>>>(
                    qsrcb + off, WqT, nullptr, qb, D, D, 1.f, 0, 0, 0);
            gemm_bf16_kernel<u16, false, false, false, false>
                <<<dim3(D/128, gb*L/128), blk, 0, stream>>>(
                    kvsrcb + off, WkT, nullptr, kb, D, D, 1.f, 0, 0, 0);
            gemm_bf16_kernel<u16, false, false, false, false>
                <<<dim3(D/128, gb*L/128), blk, 0, stream>>>(
                    kvsrcb + off, WvT, nullptr, vb, D, D, 1.f, 0, 0, 0);
            transpose_b2b_kernel<<<dim3(D/32, L/32, gb), blk, 0, stream>>>(
                vb, vtb, L, D, LD, LD);
            if (causal) {
                gemm_bf16_kernel<u16, false, false, true, false>
                    <<<dim3(L/128, L/128, gb), blk, 0, stream>>>(
                        qb, kb, nullptr, Pb, D, L, scale, LD, LD, LLs);
            } else {
                gemm_bf16_kernel<u16, false, false, false, false>
                    <<<dim3(L/128, L/128, gb), blk, 0, stream>>>(
                        qb, kb, nullptr, Pb, D, L, scale, LD, LD, LLs);
            }
            softmax_bf16_kernel<<<dim3(L, gb), blk, 0, stream>>>(Pb, L, causal, LLs);
            if (causal) {
                gemm_bf16_kernel<float, false, false, false, true>
                    <<<dim3(D/128, L/128, gb), blk, 0, stream>>>(
                        Pb, vtb, nullptr, attnb, L, D, 1.f, LLs, LD, LD);
            } else {
                gemm_bf16_kernel<float, false, false, false, false>
                    <<<dim3(D/128, L/128, gb), blk, 0, stream>>>(
                        Pb, vtb, nullptr, attnb, L, D, 1.f, LLs, LD, LD);
            }
            add_ln_kernel<<<dim3(gb * L), blk, 0, stream>>>(
                resid + off, attnb, gamma, beta, dst + off,
                dstb ? dstb + off : nullptr, D);
        }
    };

    // ---- Phase A: self-attention (causal). o1 fp32 -> d_out, o1b -> actb2 ----
    f2b_kernel<<<dim3(BLD / 2048), blk, 0, stream>>>(x, actb1);       // xb
    attn_phase(actb1, actb1, WqTs, WkTs, WvTs, x, out, actb2, 1);

    // ---- Phase B: cross-attention. o2 fp32 -> ws, o2b -> actb1 ----
    f2b_kernel<<<dim3(BLD / 2048), blk, 0, stream>>>(ctx, actb1);     // ctxb
    // o2b overwrites actb1 rows only after that group's k/v are consumed.
    attn_phase(actb2, actb1, WqTc, WkTc, WvTc, out, o2, actb1, 0);

    // ---- Phase C: FFN + LN, row-chunked through scratch ----
    {
        long mc = (long)(remain / ((size_t)H * 2 + (size_t)D * 4));
        mc = (mc / 128) * 128;
        if (mc > BL) mc = BL;
        if (mc < 128) mc = 128;
        for (long m0 = 0; m0 < BL; m0 += mc) {
            const long rows = (BL - m0) < mc ? (BL - m0) : mc;
            u16* h = (u16*)scratch;                          // [rows, H] bf16
            float* ff = (float*)(scratch + (size_t)rows * H * 2);  // [rows, D]
            gemm_bf16_kernel<u16, true, true, false, false>
                <<<dim3(H/128, rows/128), blk, 0, stream>>>(
                    actb1 + m0 * D, W1T, b1, h, D, H, 1.f, 0, 0, 0);
            gemm_bf16_kernel<float, true, false, false, false>
                <<<dim3(D/128, rows/128), blk, 0, stream>>>(
                    h, W2T, b2, ff, H, D, 1.f, 0, 0, 0);
            add_ln_kernel<<<dim3(rows), blk, 0, stream>>>(
                o2 + m0 * D, ff, gamma, beta, out + m0 * D, nullptr, D);
        }
    }
}